// Round 1
// baseline (1042.264 us; speedup 1.0000x reference)
//
#include <hip/hip_runtime.h>
#include <math.h>

// NoisyTopKRouter fused kernel (f32, correctness-first baseline).
// Shapes: hidden_states [N=16384][H=4096], noise [N][64],
//         w_gate [64][H], w_noise [64][H].
// Outputs (flat f32 in d_out): gate_weights [N][64], top2 indices as float [N][2],
//         router_logits [N][64].

#define BM 32     // tokens per block
#define BK 32     // K-chunk
#define EE 64     // experts
#define E2 128    // gate+noise logit columns

__global__ __launch_bounds__(256) void router_fused(
    const float* __restrict__ hs,
    const float* __restrict__ noise,
    const float* __restrict__ wg,
    const float* __restrict__ wn,
    float* __restrict__ out_gate,
    float* __restrict__ out_idx,
    float* __restrict__ out_logits,
    int Ntok, int Hdim)
{
    __shared__ float As[BM][BK + 4];     // +4 keeps float4 alignment, breaks pow2 stride
    __shared__ float Bs[E2][BK + 4];
    __shared__ float Ls[BM][E2 + 1];     // +1 -> conflict-free per-token scalar reads

    const int tid = threadIdx.x;
    const int m0  = blockIdx.x * BM;
    const int tx  = tid & 31;   // expert group: experts 4*tx .. 4*tx+3
    const int ty  = tid >> 5;   // token group:  tokens  4*ty .. 4*ty+3

    float acc[4][4] = {{0.f, 0.f, 0.f, 0.f}, {0.f, 0.f, 0.f, 0.f},
                       {0.f, 0.f, 0.f, 0.f}, {0.f, 0.f, 0.f, 0.f}};

    const int arow = tid >> 3;        // 0..31
    const int ac4  = (tid & 7) * 4;   // 0,4,..,28

    for (int k0 = 0; k0 < Hdim; k0 += BK) {
        // ---- stage A tile: BM x BK (one float4 per thread) ----
        {
            float4 v = *reinterpret_cast<const float4*>(
                hs + (size_t)(m0 + arow) * Hdim + k0 + ac4);
            *reinterpret_cast<float4*>(&As[arow][ac4]) = v;
        }
        // ---- stage B tile: E2 x BK (rows 0..63 = w_gate, 64..127 = w_noise) ----
        #pragma unroll
        for (int j = 0; j < 4; ++j) {
            int fid = tid + 256 * j;
            int row = fid >> 3;             // 0..127
            int c4  = (fid & 7) * 4;
            const float* src = (row < EE) ? (wg + (size_t)row * Hdim)
                                          : (wn + (size_t)(row - EE) * Hdim);
            float4 v = *reinterpret_cast<const float4*>(src + k0 + c4);
            *reinterpret_cast<float4*>(&Bs[row][c4]) = v;
        }
        __syncthreads();

        // ---- 4x4 register-tile FMA over this K-chunk ----
        #pragma unroll
        for (int kk = 0; kk < BK; kk += 4) {
            float4 a[4], b[4];
            #pragma unroll
            for (int r = 0; r < 4; ++r)
                a[r] = *reinterpret_cast<const float4*>(&As[ty * 4 + r][kk]);
            #pragma unroll
            for (int c = 0; c < 4; ++c)
                b[c] = *reinterpret_cast<const float4*>(&Bs[tx * 4 + c][kk]);
            #pragma unroll
            for (int r = 0; r < 4; ++r)
                #pragma unroll
                for (int c = 0; c < 4; ++c) {
                    acc[r][c] = fmaf(a[r].x, b[c].x, acc[r][c]);
                    acc[r][c] = fmaf(a[r].y, b[c].y, acc[r][c]);
                    acc[r][c] = fmaf(a[r].z, b[c].z, acc[r][c]);
                    acc[r][c] = fmaf(a[r].w, b[c].w, acc[r][c]);
                }
        }
        __syncthreads();
    }

    // ---- stash logits tile to LDS ----
    #pragma unroll
    for (int r = 0; r < 4; ++r)
        #pragma unroll
        for (int c = 0; c < 4; ++c)
            Ls[ty * 4 + r][tx * 4 + c] = acc[r][c];
    __syncthreads();

    // ---- per-token epilogue: one thread per token ----
    if (tid < BM) {
        const int t   = tid;
        const int tok = m0 + t;
        const float* nrow = noise + (size_t)tok * EE;
        float* lrow = out_logits + (size_t)tok * EE;

        float m = -3.4e38f;
        for (int e = 0; e < EE; ++e) {
            float g  = Ls[t][e];
            float nv = Ls[t][EE + e];
            // stable softplus, matches jax.nn.softplus = max(x,0)+log1p(exp(-|x|))
            float sp = fmaxf(nv, 0.f) + log1pf(expf(-fabsf(nv)));
            float l  = fmaf(nrow[e], sp, g);   // NOISE_STD = 1.0
            lrow[e]  = l;
            Ls[t][e] = l;
            m = fmaxf(m, l);
        }

        float Z = 0.f;
        float p1 = -1.f, p2 = -1.f;
        int   i1 = 0,    i2 = 0;
        for (int e = 0; e < EE; ++e) {
            float p = expf(Ls[t][e] - m);
            Z += p;
            if (p > p1)      { p2 = p1; i2 = i1; p1 = p; i1 = e; }  // strict >: ties -> lower idx
            else if (p > p2) { p2 = p;  i2 = e; }
        }
        float q1 = p1 / Z, q2 = p2 / Z;
        float denom = q1 + q2 + 1e-9f;
        float w1 = q1 / denom, w2 = q2 / denom;

        out_idx[(size_t)tok * 2 + 0] = (float)i1;
        out_idx[(size_t)tok * 2 + 1] = (float)i2;

        float* grow = out_gate + (size_t)tok * EE;
        for (int e = 0; e < EE; ++e) {
            float v = (e == i1) ? w1 : ((e == i2) ? w2 : 0.f);
            grow[e] = v;
        }
    }
}

extern "C" void kernel_launch(void* const* d_in, const int* in_sizes, int n_in,
                              void* d_out, int out_size, void* d_ws, size_t ws_size,
                              hipStream_t stream) {
    const float* hs    = (const float*)d_in[0];
    const float* noise = (const float*)d_in[1];
    const float* wg    = (const float*)d_in[2];
    const float* wn    = (const float*)d_in[3];

    const int Ntok = in_sizes[1] / EE;        // noise is [N][64]
    const int Hdim = in_sizes[2] / EE;        // w_gate is [64][H]

    float* out_gate   = (float*)d_out;
    float* out_idx    = out_gate + (size_t)Ntok * EE;
    float* out_logits = out_idx  + (size_t)Ntok * 2;

    dim3 grid(Ntok / BM), block(256);
    hipLaunchKernelGGL(router_fused, grid, block, 0, stream,
                       hs, noise, wg, wn, out_gate, out_idx, out_logits, Ntok, Hdim);
}

// Round 2
// 390.626 us; speedup vs baseline: 2.6682x; 2.6682x over previous
//
#include <hip/hip_runtime.h>
#include <math.h>

// NoisyTopKRouter fused kernel, round 2: conflict-free LDS layout.
// Shapes: hidden_states [N=16384][H=4096], noise [N][64],
//         w_gate [64][H], w_noise [64][H].
// Outputs (flat f32): gate_weights [N][64], top2 idx as float [N][2], logits [N][64].

#define BM 32     // tokens per block
#define BK 32     // K-chunk (8 granules of 4 floats)
#define EE 64     // experts
#define E2 128    // gate+noise logit columns

__global__ __launch_bounds__(256) void router_fused(
    const float* __restrict__ hs,
    const float* __restrict__ noise,
    const float* __restrict__ wg,
    const float* __restrict__ wn,
    float* __restrict__ out_gate,
    float* __restrict__ out_idx,
    float* __restrict__ out_logits,
    int Ntok, int Hdim)
{
    // A: row-major padded (reads are wave-broadcast -> conflict-free).
    __shared__ float As[BM][BK + 4];
    // B: exact 32-dword rows, granule-XOR swizzled, addressed as float4.
    //    phys float4 index = col*8 + (g ^ (col&7))  -- conflict-free b128 reads
    __shared__ float4 Bs4[E2 * 8];
    // logits tile for epilogue (stride 129 dwords -> conflict-free scalar reads)
    __shared__ float Ls[BM][E2 + 1];

    const int tid = threadIdx.x;
    const int m0  = blockIdx.x * BM;
    const int tx  = tid & 31;        // lane-col base: cols {tx, tx+32, tx+64, tx+96}
    const int ty  = tid >> 5;        // token group: tokens 4*ty .. 4*ty+3
    const int sw  = tx & 7;          // per-thread B swizzle key (col&7 == tx&7)

    float acc[4][4] = {{0.f,0.f,0.f,0.f},{0.f,0.f,0.f,0.f},
                       {0.f,0.f,0.f,0.f},{0.f,0.f,0.f,0.f}};

    // ---- hoisted staging addresses (tid-constant) ----
    const int arow = tid >> 3;          // 0..31
    const int ac4  = (tid & 7) * 4;     // 0,4,..,28
    const float* srcA = hs + (size_t)(m0 + arow) * Hdim + ac4;

    const float* srcB[4];
    int dstB[4];
    #pragma unroll
    for (int j = 0; j < 4; ++j) {
        int fid = tid + 256 * j;
        int col = fid >> 3;             // 0..127
        int g   = fid & 7;              // granule
        srcB[j] = ((col < EE) ? (wg + (size_t)col * Hdim)
                              : (wn + (size_t)(col - EE) * Hdim)) + g * 4;
        dstB[j] = col * 8 + (g ^ (col & 7));
    }
    int colbase[4];
    #pragma unroll
    for (int c = 0; c < 4; ++c) colbase[c] = (tx + 32 * c) * 8;

    for (int k0 = 0; k0 < Hdim; k0 += BK) {
        // ---- stage A tile: one float4 per thread ----
        *reinterpret_cast<float4*>(&As[arow][ac4]) =
            *reinterpret_cast<const float4*>(srcA + k0);
        // ---- stage B tile: 4 float4 per thread, swizzled dest ----
        #pragma unroll
        for (int j = 0; j < 4; ++j)
            Bs4[dstB[j]] = *reinterpret_cast<const float4*>(srcB[j] + k0);
        __syncthreads();

        // ---- register-tile FMA: 8 granules x (4 tok x 4 col x 4 k) ----
        #pragma unroll
        for (int g = 0; g < 8; ++g) {
            float4 a[4], b[4];
            #pragma unroll
            for (int r = 0; r < 4; ++r)
                a[r] = *reinterpret_cast<const float4*>(&As[ty * 4 + r][g * 4]);
            #pragma unroll
            for (int c = 0; c < 4; ++c)
                b[c] = Bs4[colbase[c] + (g ^ sw)];
            #pragma unroll
            for (int r = 0; r < 4; ++r)
                #pragma unroll
                for (int c = 0; c < 4; ++c) {
                    acc[r][c] = fmaf(a[r].x, b[c].x, acc[r][c]);
                    acc[r][c] = fmaf(a[r].y, b[c].y, acc[r][c]);
                    acc[r][c] = fmaf(a[r].z, b[c].z, acc[r][c]);
                    acc[r][c] = fmaf(a[r].w, b[c].w, acc[r][c]);
                }
        }
        __syncthreads();
    }

    // ---- stash logits tile to LDS (col = tx + 32c mapping) ----
    #pragma unroll
    for (int r = 0; r < 4; ++r)
        #pragma unroll
        for (int c = 0; c < 4; ++c)
            Ls[ty * 4 + r][tx + 32 * c] = acc[r][c];
    __syncthreads();

    // ---- per-token epilogue: one thread per token ----
    if (tid < BM) {
        const int t   = tid;
        const int tok = m0 + t;
        const float* nrow = noise + (size_t)tok * EE;
        float* lrow = out_logits + (size_t)tok * EE;

        float m = -3.4e38f;
        for (int e = 0; e < EE; ++e) {
            float g  = Ls[t][e];
            float nv = Ls[t][EE + e];
            float sp = fmaxf(nv, 0.f) + log1pf(expf(-fabsf(nv)));  // stable softplus
            float l  = fmaf(nrow[e], sp, g);                       // NOISE_STD = 1
            lrow[e]  = l;
            Ls[t][e] = l;
            m = fmaxf(m, l);
        }

        float Z = 0.f;
        float p1 = -1.f, p2 = -1.f;
        int   i1 = 0,    i2 = 0;
        for (int e = 0; e < EE; ++e) {
            float p = expf(Ls[t][e] - m);
            Z += p;
            if (p > p1)      { p2 = p1; i2 = i1; p1 = p; i1 = e; }  // ties -> lower idx
            else if (p > p2) { p2 = p;  i2 = e; }
        }
        float q1 = p1 / Z, q2 = p2 / Z;
        float denom = q1 + q2 + 1e-9f;
        float w1 = q1 / denom, w2 = q2 / denom;

        out_idx[(size_t)tok * 2 + 0] = (float)i1;
        out_idx[(size_t)tok * 2 + 1] = (float)i2;

        float* grow = out_gate + (size_t)tok * EE;
        for (int e = 0; e < EE; ++e)
            grow[e] = (e == i1) ? w1 : ((e == i2) ? w2 : 0.f);
    }
}

extern "C" void kernel_launch(void* const* d_in, const int* in_sizes, int n_in,
                              void* d_out, int out_size, void* d_ws, size_t ws_size,
                              hipStream_t stream) {
    const float* hs    = (const float*)d_in[0];
    const float* noise = (const float*)d_in[1];
    const float* wg    = (const float*)d_in[2];
    const float* wn    = (const float*)d_in[3];

    const int Ntok = in_sizes[1] / EE;    // noise is [N][64]
    const int Hdim = in_sizes[2] / EE;    // w_gate is [64][H]

    float* out_gate   = (float*)d_out;
    float* out_idx    = out_gate + (size_t)Ntok * EE;
    float* out_logits = out_idx  + (size_t)Ntok * 2;

    dim3 grid(Ntok / BM), block(256);
    hipLaunchKernelGGL(router_fused, grid, block, 0, stream,
                       hs, noise, wg, wn, out_gate, out_idx, out_logits, Ntok, Hdim);
}

// Round 3
// 377.416 us; speedup vs baseline: 2.7616x; 1.0350x over previous
//
#include <hip/hip_runtime.h>
#include <math.h>

// NoisyTopKRouter fused kernel, round 3:
//   - double-buffered LDS + global_load_lds (16B) prefetch pipeline (T3 2-phase)
//   - TM=8 x TN=4 register tile (BM=64 tokens/block, grid = 256 = 1 block/CU)
//   - B swizzle moved to the global SOURCE side (linear LDS dest), same XOR on read
// Outputs (flat f32): gate_weights [N][64], top2 idx as float [N][2], logits [N][64].

#define BM 64     // tokens per block
#define BK 32     // K-chunk (8 granules of 4 floats)
#define EE 64     // experts
#define E2 128    // gate+noise logit columns
#define TM 8      // tokens per thread
#define TN 4      // cols per thread

__device__ __forceinline__ void gload_lds16(const float* g, float* l) {
    __builtin_amdgcn_global_load_lds(
        (const __attribute__((address_space(1))) void*)(g),
        (__attribute__((address_space(3))) void*)(l),
        16, 0, 0);
}

__global__ __launch_bounds__(256) void router_fused(
    const float* __restrict__ hs,
    const float* __restrict__ noise,
    const float* __restrict__ wg,
    const float* __restrict__ wn,
    float* __restrict__ out_gate,
    float* __restrict__ out_idx,
    float* __restrict__ out_logits,
    int Ntok, int Hdim)
{
    // A: linear [row][k] (row stride 32 floats = 128B; reads are 2-addr broadcast -> free)
    __shared__ float  As[2][BM * BK];
    // B: linear granule slots, swizzle applied on the GLOBAL source side.
    //    slot(col, g') holds global granule g'^(col&7); read with same XOR.
    __shared__ float4 Bs4[2][E2 * 8];
    // logits tile for epilogue (stride 129 -> conflict-free scalar reads)
    __shared__ float  Ls[BM][E2 + 1];

    const int tid = threadIdx.x;
    const int m0  = blockIdx.x * BM;
    const int tx  = tid & 31;        // cols {tx, tx+32, tx+64, tx+96}
    const int ty  = tid >> 5;        // token group: tokens 8*ty .. 8*ty+7
    const int sw  = tx & 7;          // B read-side swizzle key (== col&7)

    float acc[TM][TN];
    #pragma unroll
    for (int r = 0; r < TM; ++r)
        #pragma unroll
        for (int c = 0; c < TN; ++c) acc[r][c] = 0.f;

    // ---- staging sources (advance by BK per chunk) ----
    // A: 512 float4 slots, 2 per thread. slot = tid + 256*j, row = slot>>3, g = slot&7.
    const float* pA[2];
    #pragma unroll
    for (int j = 0; j < 2; ++j) {
        int slot = tid + 256 * j;
        pA[j] = hs + (size_t)(m0 + (slot >> 3)) * Hdim + (slot & 7) * 4;
    }
    // B: 1024 float4 slots, 4 per thread. slot = tid + 256*j, col = slot>>3, g' = slot&7;
    //    global granule = g' ^ (col&7)  (source-side swizzle)
    const float* pB[4];
    #pragma unroll
    for (int j = 0; j < 4; ++j) {
        int slot = tid + 256 * j;
        int col  = slot >> 3;
        int gp   = slot & 7;
        const float* wrow = (col < EE) ? (wg + (size_t)col * Hdim)
                                       : (wn + (size_t)(col - EE) * Hdim);
        pB[j] = wrow + ((gp ^ (col & 7)) * 4);
    }

    int colbase[TN];
    #pragma unroll
    for (int c = 0; c < TN; ++c) colbase[c] = (tx + 32 * c) * 8;

    #define STAGE(buf)                                                        \
        do {                                                                  \
            _Pragma("unroll")                                                 \
            for (int j = 0; j < 2; ++j)                                       \
                gload_lds16(pA[j], &As[buf][(tid + 256 * j) * 4]);            \
            _Pragma("unroll")                                                 \
            for (int j = 0; j < 4; ++j)                                       \
                gload_lds16(pB[j], (float*)&Bs4[buf][tid + 256 * j]);         \
            _Pragma("unroll")                                                 \
            for (int j = 0; j < 2; ++j) pA[j] += BK;                          \
            _Pragma("unroll")                                                 \
            for (int j = 0; j < 4; ++j) pB[j] += BK;                          \
        } while (0)

    #define COMPUTE(buf)                                                      \
        do {                                                                  \
            const float*  Ab = As[buf];                                       \
            const float4* Bb = Bs4[buf];                                      \
            _Pragma("unroll")                                                 \
            for (int g = 0; g < 8; ++g) {                                     \
                float4 b[TN];                                                 \
                _Pragma("unroll")                                             \
                for (int c = 0; c < TN; ++c)                                  \
                    b[c] = Bb[colbase[c] + (g ^ sw)];                         \
                float4 a[TM];                                                 \
                _Pragma("unroll")                                             \
                for (int r = 0; r < TM; ++r)                                  \
                    a[r] = *reinterpret_cast<const float4*>(                  \
                        &Ab[(ty * TM + r) * BK + g * 4]);                     \
                _Pragma("unroll")                                             \
                for (int r = 0; r < TM; ++r)                                  \
                    _Pragma("unroll")                                         \
                    for (int c = 0; c < TN; ++c) {                            \
                        acc[r][c] = fmaf(a[r].x, b[c].x, acc[r][c]);          \
                        acc[r][c] = fmaf(a[r].y, b[c].y, acc[r][c]);          \
                        acc[r][c] = fmaf(a[r].z, b[c].z, acc[r][c]);          \
                        acc[r][c] = fmaf(a[r].w, b[c].w, acc[r][c]);          \
                    }                                                         \
            }                                                                 \
        } while (0)

    // ---- prologue: stage chunk 0 ----
    STAGE(0);
    __syncthreads();

    const int nch = Hdim / BK;   // 128 (even)
    for (int kc = 0; kc < nch; kc += 2) {
        STAGE(1);                          // chunk kc+1, in flight during compute
        COMPUTE(0);
        __syncthreads();                   // drains vmcnt -> buf1 ready
        if (kc + 2 < nch) STAGE(0);        // chunk kc+2
        COMPUTE(1);
        __syncthreads();
    }

    // ---- stash logits tile to LDS ----
    #pragma unroll
    for (int r = 0; r < TM; ++r)
        #pragma unroll
        for (int c = 0; c < TN; ++c)
            Ls[ty * TM + r][tx + 32 * c] = acc[r][c];
    __syncthreads();

    // ---- per-token epilogue: one thread per token (wave 0) ----
    if (tid < BM) {
        const int t   = tid;
        const int tok = m0 + t;
        const float* nrow = noise + (size_t)tok * EE;
        float* lrow = out_logits + (size_t)tok * EE;

        float m = -3.4e38f;
        for (int e = 0; e < EE; ++e) {
            float gv = Ls[t][e];
            float nv = Ls[t][EE + e];
            float sp = fmaxf(nv, 0.f) + log1pf(expf(-fabsf(nv)));  // stable softplus
            float l  = fmaf(nrow[e], sp, gv);                      // NOISE_STD = 1
            lrow[e]  = l;
            Ls[t][e] = l;
            m = fmaxf(m, l);
        }

        float Z = 0.f;
        float p1 = -1.f, p2 = -1.f;
        int   i1 = 0,    i2 = 0;
        for (int e = 0; e < EE; ++e) {
            float p = expf(Ls[t][e] - m);
            Z += p;
            if (p > p1)      { p2 = p1; i2 = i1; p1 = p; i1 = e; }  // ties -> lower idx
            else if (p > p2) { p2 = p;  i2 = e; }
        }
        float q1 = p1 / Z, q2 = p2 / Z;
        float denom = q1 + q2 + 1e-9f;
        float w1 = q1 / denom, w2 = q2 / denom;

        out_idx[(size_t)tok * 2 + 0] = (float)i1;
        out_idx[(size_t)tok * 2 + 1] = (float)i2;

        float* grow = out_gate + (size_t)tok * EE;
        for (int e = 0; e < EE; ++e)
            grow[e] = (e == i1) ? w1 : ((e == i2) ? w2 : 0.f);
    }
}

extern "C" void kernel_launch(void* const* d_in, const int* in_sizes, int n_in,
                              void* d_out, int out_size, void* d_ws, size_t ws_size,
                              hipStream_t stream) {
    const float* hs    = (const float*)d_in[0];
    const float* noise = (const float*)d_in[1];
    const float* wg    = (const float*)d_in[2];
    const float* wn    = (const float*)d_in[3];

    const int Ntok = in_sizes[1] / EE;    // noise is [N][64]
    const int Hdim = in_sizes[2] / EE;    // w_gate is [64][H]

    float* out_gate   = (float*)d_out;
    float* out_idx    = out_gate + (size_t)Ntok * EE;
    float* out_logits = out_idx  + (size_t)Ntok * 2;

    dim3 grid(Ntok / BM), block(256);
    hipLaunchKernelGGL(router_fused, grid, block, 0, stream,
                       hs, noise, wg, wn, out_gate, out_idx, out_logits, Ntok, Hdim);
}

// Round 4
// 222.702 us; speedup vs baseline: 4.6801x; 1.6947x over previous
//
#include <hip/hip_runtime.h>
#include <math.h>

// NoisyTopKRouter, round 4: bf16x3 split-precision MFMA path.
//   logits = hs(f32) x W^T via 6 bf16 MFMA products (~f32 accuracy).
//   Pre-kernel packs W into MFMA B-fragment layout (3 terms, bf16) in d_ws.
//   Main: grid 256, 4 waves/block, K-split across waves, A from HBM->reg->split,
//   B-frags from L2, no LDS in main loop; LDS reduce + fused epilogue.
// Outputs (flat f32): gate_weights [N][64], top2 idx as float [N][2], logits [N][64].

typedef float   f32x4   __attribute__((ext_vector_type(4)));
typedef __bf16  bf16x8  __attribute__((ext_vector_type(8)));
typedef unsigned short ushort8 __attribute__((ext_vector_type(8)));

#define EE 64     // experts
#define E2 128    // gate+noise logit columns
#define MT 4      // 16-row m-tiles per wave (64 tokens)
#define NT 8      // 16-col n-tiles (128 cols)
#define BM 64     // tokens per block

__device__ __forceinline__ unsigned short bf16_rne(float f) {
    unsigned int u = __float_as_uint(f);
    u += 0x7fffu + ((u >> 16) & 1u);
    return (unsigned short)(u >> 16);
}
__device__ __forceinline__ float bf16_f32(unsigned short h) {
    return __uint_as_float(((unsigned int)h) << 16);
}
__device__ __forceinline__ void split3(float a, unsigned short& h1,
                                       unsigned short& h2, unsigned short& h3) {
    h1 = bf16_rne(a);
    float r  = a - bf16_f32(h1);     // exact
    h2 = bf16_rne(r);
    float r2 = r - bf16_f32(h2);     // exact
    h3 = bf16_rne(r2);
}

// ---- pre-kernel: pack W (gate rows 0..63, noise rows 64..127) into B-frag order.
// Fragment (16x16x32 bf16, verified layout): lane l holds col=l&15, k=(l>>4)*8+j.
// Packed ushort addr: ((ks*8 + nt)*3 + term)*512 + lane*8 + j   (ks = k/32)
__global__ __launch_bounds__(256) void pack_b(
    const float* __restrict__ wg, const float* __restrict__ wn,
    unsigned short* __restrict__ bp, int Hdim)
{
    int pair = blockIdx.x * 4 + (threadIdx.x >> 6);   // (ks, nt)
    int l    = threadIdx.x & 63;
    int ks   = pair >> 3;
    int nt   = pair & 7;
    int col  = nt * 16 + (l & 15);
    int k    = ks * 32 + ((l >> 4) * 8);
    const float* wrow = (col < EE) ? (wg + (size_t)col * Hdim)
                                   : (wn + (size_t)(col - EE) * Hdim);
    float4 v0 = *reinterpret_cast<const float4*>(wrow + k);
    float4 v1 = *reinterpret_cast<const float4*>(wrow + k + 4);
    float vals[8] = {v0.x, v0.y, v0.z, v0.w, v1.x, v1.y, v1.z, v1.w};
    ushort8 t1, t2, t3;
    #pragma unroll
    for (int j = 0; j < 8; ++j) {
        unsigned short a, b, c;
        split3(vals[j], a, b, c);
        t1[j] = a; t2[j] = b; t3[j] = c;
    }
    size_t base = ((size_t)(ks * 8 + nt) * 3) * 512 + (size_t)l * 8;
    *reinterpret_cast<ushort8*>(bp + base        ) = t1;
    *reinterpret_cast<ushort8*>(bp + base + 512  ) = t2;
    *reinterpret_cast<ushort8*>(bp + base + 1024 ) = t3;
}

#define MFMA(a, b, c) __builtin_amdgcn_mfma_f32_16x16x32_bf16((a), (b), (c), 0, 0, 0)

__global__ __launch_bounds__(256, 1) void router_mfma(
    const float* __restrict__ hs,
    const float* __restrict__ noise,
    const unsigned short* __restrict__ bp,
    float* __restrict__ out_gate,
    float* __restrict__ out_idx,
    float* __restrict__ out_logits,
    int Ntok, int Hdim)
{
    __shared__ float Lred[BM][E2 + 5];   // stride 133: 5t+e mod 32 -> conflict-free

    const int tid  = threadIdx.x;
    const int lane = tid & 63;
    const int w    = tid >> 6;           // wave id 0..3 (k-split)
    const int m0   = blockIdx.x * BM;

    const int kpw   = Hdim >> 2;         // k per wave (1024)
    const int steps = kpw >> 5;          // 32

    f32x4 acc[MT][NT];
    #pragma unroll
    for (int mt = 0; mt < MT; ++mt)
        #pragma unroll
        for (int nt = 0; nt < NT; ++nt)
            acc[mt][nt] = f32x4{0.f, 0.f, 0.f, 0.f};

    // A sources: lane l covers row (l&15) of its m-tile, k-octet (l>>4)*8.
    const float* pa[MT];
    #pragma unroll
    for (int mt = 0; mt < MT; ++mt)
        pa[mt] = hs + (size_t)(m0 + mt * 16 + (lane & 15)) * Hdim
                    + (size_t)w * kpw + ((lane >> 4) * 8);

    // B source: this wave's k-window, packed-frag order.
    const unsigned short* pb = bp + (size_t)(w * steps) * 12288 + (size_t)lane * 8;

    for (int s = 0; s < steps; ++s) {
        // ---- A: 8 f32 per m-tile per lane, straight from HBM (full 128B lines) ----
        float4 av0[MT], av1[MT];
        #pragma unroll
        for (int mt = 0; mt < MT; ++mt) {
            av0[mt] = *reinterpret_cast<const float4*>(pa[mt]);
            av1[mt] = *reinterpret_cast<const float4*>(pa[mt] + 4);
            pa[mt] += 32;
        }
        // ---- split into 3 bf16 terms, already in A-frag layout ----
        bf16x8 a1[MT], a2[MT], a3[MT];
        #pragma unroll
        for (int mt = 0; mt < MT; ++mt) {
            float vals[8] = {av0[mt].x, av0[mt].y, av0[mt].z, av0[mt].w,
                             av1[mt].x, av1[mt].y, av1[mt].z, av1[mt].w};
            ushort8 u1, u2, u3;
            #pragma unroll
            for (int j = 0; j < 8; ++j) {
                unsigned short h1, h2, h3;
                split3(vals[j], h1, h2, h3);
                u1[j] = h1; u2[j] = h2; u3[j] = h3;
            }
            a1[mt] = __builtin_bit_cast(bf16x8, u1);
            a2[mt] = __builtin_bit_cast(bf16x8, u2);
            a3[mt] = __builtin_bit_cast(bf16x8, u3);
        }
        // ---- B frags from L2 + 6-term MFMA ----
        #pragma unroll
        for (int nt = 0; nt < NT; ++nt) {
            bf16x8 b1 = __builtin_bit_cast(bf16x8,
                *reinterpret_cast<const ushort8*>(pb + (nt * 3 + 0) * 512));
            bf16x8 b2 = __builtin_bit_cast(bf16x8,
                *reinterpret_cast<const ushort8*>(pb + (nt * 3 + 1) * 512));
            bf16x8 b3 = __builtin_bit_cast(bf16x8,
                *reinterpret_cast<const ushort8*>(pb + (nt * 3 + 2) * 512));
            #pragma unroll
            for (int mt = 0; mt < MT; ++mt) {
                f32x4 c = acc[mt][nt];
                c = MFMA(a1[mt], b1, c);
                c = MFMA(a1[mt], b2, c);
                c = MFMA(a2[mt], b1, c);
                c = MFMA(a2[mt], b2, c);
                c = MFMA(a1[mt], b3, c);
                c = MFMA(a3[mt], b1, c);
                acc[mt][nt] = c;
            }
        }
        pb += 12288;
    }

    // ---- cross-wave K reduction via LDS (sequential add phases) ----
    // C/D frag (verified): reg r -> row=(lane>>4)*4+r, col=lane&15.
    #pragma unroll
    for (int ph = 0; ph < 4; ++ph) {
        if (w == ph) {
            #pragma unroll
            for (int mt = 0; mt < MT; ++mt)
                #pragma unroll
                for (int nt = 0; nt < NT; ++nt)
                    #pragma unroll
                    for (int r = 0; r < 4; ++r) {
                        int row = mt * 16 + (lane >> 4) * 4 + r;
                        int col = nt * 16 + (lane & 15);
                        if (ph == 0) Lred[row][col]  = acc[mt][nt][r];
                        else         Lred[row][col] += acc[mt][nt][r];
                    }
        }
        __syncthreads();
    }

    // ---- per-token epilogue (proven path): one thread per token ----
    if (tid < BM) {
        const int t   = tid;
        const int tok = m0 + t;
        const float* nrow = noise + (size_t)tok * EE;
        float* lrow = out_logits + (size_t)tok * EE;

        float m = -3.4e38f;
        for (int e = 0; e < EE; ++e) {
            float gv = Lred[t][e];
            float nv = Lred[t][EE + e];
            float sp = fmaxf(nv, 0.f) + log1pf(expf(-fabsf(nv)));  // stable softplus
            float l  = fmaf(nrow[e], sp, gv);                      // NOISE_STD = 1
            lrow[e]  = l;
            Lred[t][e] = l;
            m = fmaxf(m, l);
        }

        float Z = 0.f;
        float p1 = -1.f, p2 = -1.f;
        int   i1 = 0,    i2 = 0;
        for (int e = 0; e < EE; ++e) {
            float p = expf(Lred[t][e] - m);
            Z += p;
            if (p > p1)      { p2 = p1; i2 = i1; p1 = p; i1 = e; }  // ties -> lower idx
            else if (p > p2) { p2 = p;  i2 = e; }
        }
        float q1 = p1 / Z, q2 = p2 / Z;
        float denom = q1 + q2 + 1e-9f;
        float w1 = q1 / denom, w2 = q2 / denom;

        out_idx[(size_t)tok * 2 + 0] = (float)i1;
        out_idx[(size_t)tok * 2 + 1] = (float)i2;

        float* grow = out_gate + (size_t)tok * EE;
        for (int e = 0; e < EE; ++e)
            grow[e] = (e == i1) ? w1 : ((e == i2) ? w2 : 0.f);
    }
}

extern "C" void kernel_launch(void* const* d_in, const int* in_sizes, int n_in,
                              void* d_out, int out_size, void* d_ws, size_t ws_size,
                              hipStream_t stream) {
    const float* hs    = (const float*)d_in[0];
    const float* noise = (const float*)d_in[1];
    const float* wg    = (const float*)d_in[2];
    const float* wn    = (const float*)d_in[3];

    const int Ntok = in_sizes[1] / EE;    // noise is [N][64]
    const int Hdim = in_sizes[2] / EE;    // w_gate is [64][H]

    float* out_gate   = (float*)d_out;
    float* out_idx    = out_gate + (size_t)Ntok * EE;
    float* out_logits = out_idx  + (size_t)Ntok * 2;

    unsigned short* bp = (unsigned short*)d_ws;   // needs (H/32)*8*3*512*2 = 3 MB

    // pack W into MFMA B-fragment layout (3 bf16 terms)
    int pairs = (Hdim / 32) * 8;
    hipLaunchKernelGGL(pack_b, dim3(pairs / 4), dim3(256), 0, stream, wg, wn, bp, Hdim);

    hipLaunchKernelGGL(router_mfma, dim3(Ntok / BM), dim3(256), 0, stream,
                       hs, noise, bp, out_gate, out_idx, out_logits, Ntok, Hdim);
}

// Round 5
// 169.382 us; speedup vs baseline: 6.1533x; 1.3148x over previous
//
#include <hip/hip_runtime.h>
#include <math.h>

// NoisyTopKRouter, round 5: bf16x3 MFMA + occupancy/ILP fix.
//   - BM=32 (MT=2), grid=512 -> 2 blocks/CU -> 2 waves/SIMD
//   - register double-buffered A prefetch (unroll-by-2, named reg sets)
//   - same verified bf16x3 6-product math, packed-B layout, fused epilogue
// Outputs (flat f32): gate_weights [N][64], top2 idx as float [N][2], logits [N][64].

typedef float   f32x4   __attribute__((ext_vector_type(4)));
typedef __bf16  bf16x8  __attribute__((ext_vector_type(8)));
typedef unsigned short ushort8 __attribute__((ext_vector_type(8)));

#define EE 64     // experts
#define E2 128    // gate+noise logit columns
#define MT 2      // 16-row m-tiles per wave (32 tokens)
#define NT 8      // 16-col n-tiles (128 cols)
#define BM 32     // tokens per block

__device__ __forceinline__ unsigned short bf16_rne(float f) {
    unsigned int u = __float_as_uint(f);
    u += 0x7fffu + ((u >> 16) & 1u);
    return (unsigned short)(u >> 16);
}
__device__ __forceinline__ float bf16_f32(unsigned short h) {
    return __uint_as_float(((unsigned int)h) << 16);
}
__device__ __forceinline__ void split3(float a, unsigned short& h1,
                                       unsigned short& h2, unsigned short& h3) {
    h1 = bf16_rne(a);
    float r  = a - bf16_f32(h1);     // exact
    h2 = bf16_rne(r);
    float r2 = r - bf16_f32(h2);     // exact
    h3 = bf16_rne(r2);
}

// ---- pre-kernel: pack W (gate cols 0..63, noise cols 64..127) into B-frag order.
// Fragment (16x16x32 bf16, verified): lane l holds col=l&15, k=(l>>4)*8+j.
// Packed ushort addr: ((ks*8 + nt)*3 + term)*512 + lane*8 + j   (ks = k/32)
__global__ __launch_bounds__(256) void pack_b(
    const float* __restrict__ wg, const float* __restrict__ wn,
    unsigned short* __restrict__ bp, int Hdim)
{
    int pair = blockIdx.x * 4 + (threadIdx.x >> 6);   // (ks, nt)
    int l    = threadIdx.x & 63;
    int ks   = pair >> 3;
    int nt   = pair & 7;
    int col  = nt * 16 + (l & 15);
    int k    = ks * 32 + ((l >> 4) * 8);
    const float* wrow = (col < EE) ? (wg + (size_t)col * Hdim)
                                   : (wn + (size_t)(col - EE) * Hdim);
    float4 v0 = *reinterpret_cast<const float4*>(wrow + k);
    float4 v1 = *reinterpret_cast<const float4*>(wrow + k + 4);
    float vals[8] = {v0.x, v0.y, v0.z, v0.w, v1.x, v1.y, v1.z, v1.w};
    ushort8 t1, t2, t3;
    #pragma unroll
    for (int j = 0; j < 8; ++j) {
        unsigned short a, b, c;
        split3(vals[j], a, b, c);
        t1[j] = a; t2[j] = b; t3[j] = c;
    }
    size_t base = ((size_t)(ks * 8 + nt) * 3) * 512 + (size_t)l * 8;
    *reinterpret_cast<ushort8*>(bp + base        ) = t1;
    *reinterpret_cast<ushort8*>(bp + base + 512  ) = t2;
    *reinterpret_cast<ushort8*>(bp + base + 1024 ) = t3;
}

#define MFMA(a, b, c) __builtin_amdgcn_mfma_f32_16x16x32_bf16((a), (b), (c), 0, 0, 0)

__global__ __launch_bounds__(256) void router_mfma(
    const float* __restrict__ hs,
    const float* __restrict__ noise,
    const unsigned short* __restrict__ bp,
    float* __restrict__ out_gate,
    float* __restrict__ out_idx,
    float* __restrict__ out_logits,
    int Ntok, int Hdim)
{
    __shared__ float Lred[BM][E2 + 5];   // stride 133 -> conflict-free scalar reads

    const int tid  = threadIdx.x;
    const int lane = tid & 63;
    const int w    = tid >> 6;           // wave id 0..3 (k-split)
    const int m0   = blockIdx.x * BM;

    const int kpw   = Hdim >> 2;         // k per wave (1024)
    const int steps = kpw >> 5;          // 32

    f32x4 acc[MT][NT];
    #pragma unroll
    for (int mt = 0; mt < MT; ++mt)
        #pragma unroll
        for (int nt = 0; nt < NT; ++nt)
            acc[mt][nt] = f32x4{0.f, 0.f, 0.f, 0.f};

    // A sources: lane l covers row (l&15) of its m-tile, k-octet (l>>4)*8.
    const float* pa[MT];
    #pragma unroll
    for (int mt = 0; mt < MT; ++mt)
        pa[mt] = hs + (size_t)(m0 + mt * 16 + (lane & 15)) * Hdim
                    + (size_t)w * kpw + ((lane >> 4) * 8);

    // B source: this wave's k-window, packed-frag order.
    const unsigned short* pb = bp + (size_t)(w * steps) * 12288 + (size_t)lane * 8;

    #define LOADA(d0, d1)                                                     \
        do {                                                                  \
            _Pragma("unroll")                                                 \
            for (int mt = 0; mt < MT; ++mt) {                                 \
                d0[mt] = *reinterpret_cast<const float4*>(pa[mt]);            \
                d1[mt] = *reinterpret_cast<const float4*>(pa[mt] + 4);        \
                pa[mt] += 32;                                                 \
            }                                                                 \
        } while (0)

    #define COMPUTE(s0, s1)                                                   \
        do {                                                                  \
            bf16x8 A1[MT], A2[MT], A3[MT];                                    \
            _Pragma("unroll")                                                 \
            for (int mt = 0; mt < MT; ++mt) {                                 \
                float vals[8] = {s0[mt].x, s0[mt].y, s0[mt].z, s0[mt].w,      \
                                 s1[mt].x, s1[mt].y, s1[mt].z, s1[mt].w};     \
                ushort8 u1, u2, u3;                                           \
                _Pragma("unroll")                                             \
                for (int j = 0; j < 8; ++j) {                                 \
                    unsigned short h1, h2, h3;                                \
                    split3(vals[j], h1, h2, h3);                              \
                    u1[j] = h1; u2[j] = h2; u3[j] = h3;                       \
                }                                                             \
                A1[mt] = __builtin_bit_cast(bf16x8, u1);                      \
                A2[mt] = __builtin_bit_cast(bf16x8, u2);                      \
                A3[mt] = __builtin_bit_cast(bf16x8, u3);                      \
            }                                                                 \
            _Pragma("unroll")                                                 \
            for (int nt = 0; nt < NT; ++nt) {                                 \
                bf16x8 b1 = __builtin_bit_cast(bf16x8,                        \
                    *reinterpret_cast<const ushort8*>(pb + (nt * 3 + 0) * 512)); \
                bf16x8 b2 = __builtin_bit_cast(bf16x8,                        \
                    *reinterpret_cast<const ushort8*>(pb + (nt * 3 + 1) * 512)); \
                bf16x8 b3 = __builtin_bit_cast(bf16x8,                        \
                    *reinterpret_cast<const ushort8*>(pb + (nt * 3 + 2) * 512)); \
                _Pragma("unroll")                                             \
                for (int mt = 0; mt < MT; ++mt) {                             \
                    f32x4 c = acc[mt][nt];                                    \
                    c = MFMA(A1[mt], b1, c);                                  \
                    c = MFMA(A1[mt], b2, c);                                  \
                    c = MFMA(A2[mt], b1, c);                                  \
                    c = MFMA(A2[mt], b2, c);                                  \
                    c = MFMA(A1[mt], b3, c);                                  \
                    c = MFMA(A3[mt], b1, c);                                  \
                    acc[mt][nt] = c;                                          \
                }                                                             \
            }                                                                 \
            pb += 12288;                                                      \
        } while (0)

    // ---- software-pipelined main loop (unroll-by-2, named reg sets) ----
    float4 c0[MT], c1[MT], n0[MT], n1[MT];
    LOADA(c0, c1);                        // step 0
    for (int s = 0; s < steps; s += 2) {
        LOADA(n0, n1);                    // prefetch step s+1 (steps even)
        COMPUTE(c0, c1);                  // compute step s
        if (s + 2 < steps) LOADA(c0, c1); // prefetch step s+2
        COMPUTE(n0, n1);                  // compute step s+1
    }

    // ---- cross-wave K reduction via LDS (sequential add phases) ----
    // C/D frag (verified): reg r -> row=(lane>>4)*4+r, col=lane&15.
    #pragma unroll
    for (int ph = 0; ph < 4; ++ph) {
        if (w == ph) {
            #pragma unroll
            for (int mt = 0; mt < MT; ++mt)
                #pragma unroll
                for (int nt = 0; nt < NT; ++nt)
                    #pragma unroll
                    for (int r = 0; r < 4; ++r) {
                        int row = mt * 16 + (lane >> 4) * 4 + r;
                        int col = nt * 16 + (lane & 15);
                        if (ph == 0) Lred[row][col]  = acc[mt][nt][r];
                        else         Lred[row][col] += acc[mt][nt][r];
                    }
        }
        __syncthreads();
    }

    // ---- per-token epilogue (proven path): one thread per token ----
    if (tid < BM) {
        const int t   = tid;
        const int tok = m0 + t;
        const float* nrow = noise + (size_t)tok * EE;
        float* lrow = out_logits + (size_t)tok * EE;

        float m = -3.4e38f;
        for (int e = 0; e < EE; ++e) {
            float gv = Lred[t][e];
            float nv = Lred[t][EE + e];
            float sp = fmaxf(nv, 0.f) + log1pf(expf(-fabsf(nv)));  // stable softplus
            float l  = fmaf(nrow[e], sp, gv);                      // NOISE_STD = 1
            lrow[e]  = l;
            Lred[t][e] = l;
            m = fmaxf(m, l);
        }

        float Z = 0.f;
        float p1 = -1.f, p2 = -1.f;
        int   i1 = 0,    i2 = 0;
        for (int e = 0; e < EE; ++e) {
            float p = expf(Lred[t][e] - m);
            Z += p;
            if (p > p1)      { p2 = p1; i2 = i1; p1 = p; i1 = e; }  // ties -> lower idx
            else if (p > p2) { p2 = p;  i2 = e; }
        }
        float q1 = p1 / Z, q2 = p2 / Z;
        float denom = q1 + q2 + 1e-9f;
        float w1 = q1 / denom, w2 = q2 / denom;

        out_idx[(size_t)tok * 2 + 0] = (float)i1;
        out_idx[(size_t)tok * 2 + 1] = (float)i2;

        float* grow = out_gate + (size_t)tok * EE;
        for (int e = 0; e < EE; ++e)
            grow[e] = (e == i1) ? w1 : ((e == i2) ? w2 : 0.f);
    }
}

extern "C" void kernel_launch(void* const* d_in, const int* in_sizes, int n_in,
                              void* d_out, int out_size, void* d_ws, size_t ws_size,
                              hipStream_t stream) {
    const float* hs    = (const float*)d_in[0];
    const float* noise = (const float*)d_in[1];
    const float* wg    = (const float*)d_in[2];
    const float* wn    = (const float*)d_in[3];

    const int Ntok = in_sizes[1] / EE;    // noise is [N][64]
    const int Hdim = in_sizes[2] / EE;    // w_gate is [64][H]

    float* out_gate   = (float*)d_out;
    float* out_idx    = out_gate + (size_t)Ntok * EE;
    float* out_logits = out_idx  + (size_t)Ntok * 2;

    unsigned short* bp = (unsigned short*)d_ws;   // needs (H/32)*8*3*512*2 = 3 MB

    // pack W into MFMA B-fragment layout (3 bf16 terms)
    int pairs = (Hdim / 32) * 8;
    hipLaunchKernelGGL(pack_b, dim3(pairs / 4), dim3(256), 0, stream, wg, wn, bp, Hdim);

    hipLaunchKernelGGL(router_mfma, dim3(Ntok / BM), dim3(256), 0, stream,
                       hs, noise, bp, out_gate, out_idx, out_logits, Ntok, Hdim);
}

// Round 6
// 167.297 us; speedup vs baseline: 6.2300x; 1.0125x over previous
//
#include <hip/hip_runtime.h>
#include <math.h>

// NoisyTopKRouter, round 6: bf16x3 MFMA + shared-B LDS pipeline (T3 2-phase).
//   - BM=64 tokens/block, 512 threads = 8 waves (4 m-tiles x 2 k-halves), grid 256
//   - B fragments staged per step into LDS via global_load_lds (shared by 4 m-waves),
//     double-buffered, one __syncthreads per step (vmcnt(0) drain = pipeline anchor)
//   - A: HBM -> regs, parity-named double buffer; bf16x3 6-product math (proven)
// Outputs (flat f32): gate_weights [N][64], top2 idx as float [N][2], logits [N][64].

typedef float   f32x4   __attribute__((ext_vector_type(4)));
typedef __bf16  bf16x8  __attribute__((ext_vector_type(8)));
typedef unsigned short ushort8 __attribute__((ext_vector_type(8)));

#define EE 64     // experts
#define E2 128    // gate+noise logit columns
#define NT 8      // 16-col n-tiles (128 cols)
#define BM 64     // tokens per block

__device__ __forceinline__ unsigned short bf16_rne(float f) {
    unsigned int u = __float_as_uint(f);
    u += 0x7fffu + ((u >> 16) & 1u);
    return (unsigned short)(u >> 16);
}
__device__ __forceinline__ float bf16_f32(unsigned short h) {
    return __uint_as_float(((unsigned int)h) << 16);
}
__device__ __forceinline__ void split3(float a, unsigned short& h1,
                                       unsigned short& h2, unsigned short& h3) {
    h1 = bf16_rne(a);
    float r  = a - bf16_f32(h1);     // exact
    h2 = bf16_rne(r);
    float r2 = r - bf16_f32(h2);     // exact
    h3 = bf16_rne(r2);
}

__device__ __forceinline__ void gload_lds16(const void* g, void* l) {
    __builtin_amdgcn_global_load_lds(
        (const __attribute__((address_space(1))) void*)g,
        (__attribute__((address_space(3))) void*)l, 16, 0, 0);
}

// ---- pre-kernel: pack W (gate cols 0..63, noise cols 64..127) into B-frag order.
// Fragment (16x16x32 bf16, verified): lane l holds col=l&15, k=(l>>4)*8+j.
// Packed ushort addr: ((ks*8 + nt)*3 + term)*512 + lane*8 + j   (ks = k/32)
__global__ __launch_bounds__(256) void pack_b(
    const float* __restrict__ wg, const float* __restrict__ wn,
    unsigned short* __restrict__ bp, int Hdim)
{
    int pair = blockIdx.x * 4 + (threadIdx.x >> 6);   // (ks, nt)
    int l    = threadIdx.x & 63;
    int ks   = pair >> 3;
    int nt   = pair & 7;
    int col  = nt * 16 + (l & 15);
    int k    = ks * 32 + ((l >> 4) * 8);
    const float* wrow = (col < EE) ? (wg + (size_t)col * Hdim)
                                   : (wn + (size_t)(col - EE) * Hdim);
    float4 v0 = *reinterpret_cast<const float4*>(wrow + k);
    float4 v1 = *reinterpret_cast<const float4*>(wrow + k + 4);
    float vals[8] = {v0.x, v0.y, v0.z, v0.w, v1.x, v1.y, v1.z, v1.w};
    ushort8 t1, t2, t3;
    #pragma unroll
    for (int j = 0; j < 8; ++j) {
        unsigned short a, b, c;
        split3(vals[j], a, b, c);
        t1[j] = a; t2[j] = b; t3[j] = c;
    }
    size_t base = ((size_t)(ks * 8 + nt) * 3) * 512 + (size_t)l * 8;
    *reinterpret_cast<ushort8*>(bp + base        ) = t1;
    *reinterpret_cast<ushort8*>(bp + base + 512  ) = t2;
    *reinterpret_cast<ushort8*>(bp + base + 1024 ) = t3;
}

#define MFMA(a, b, c) __builtin_amdgcn_mfma_f32_16x16x32_bf16((a), (b), (c), 0, 0, 0)

__global__ __launch_bounds__(512) void router_mfma(
    const float* __restrict__ hs,
    const float* __restrict__ noise,
    const unsigned short* __restrict__ bp,
    float* __restrict__ out_gate,
    float* __restrict__ out_idx,
    float* __restrict__ out_logits,
    int Ntok, int Hdim)
{
    // B staging: [dbuf][kh][frag(0..23)*512 + lane*8 + j] ushorts -> 96 KB
    __shared__ unsigned short Bst[2][2][24 * 512];
    __shared__ float Lred[BM][E2 + 5];   // stride 133 -> conflict-free scalar reads

    const int tid  = threadIdx.x;
    const int lane = tid & 63;
    const int w    = tid >> 6;           // wave 0..7
    const int kh   = w >> 2;             // k-half 0..1
    const int mi   = w & 3;              // m-tile 0..3
    const int m0   = blockIdx.x * BM;

    const int khalf = Hdim >> 1;         // 2048
    const int steps = khalf >> 5;        // 64 (even)

    f32x4 acc[NT];
    #pragma unroll
    for (int nt = 0; nt < NT; ++nt) acc[nt] = f32x4{0.f, 0.f, 0.f, 0.f};

    // ---- A source: lane l covers row (l&15) of this wave's m-tile, k-octet (l>>4)*8
    const float* pa = hs + (size_t)(m0 + mi * 16 + (lane & 15)) * Hdim
                         + (size_t)kh * khalf + ((lane >> 4) * 8);

    // ---- B stage chunks: 3072 x 16B per step; chunk c = tid + 512*j.
    //      kh' = c/1536 and frag f = (c%1536)/64 are wave-uniform; lane varies -> lane*16B.
    const unsigned short* srcB[6];
    unsigned short* dstB[2][6];
    #pragma unroll
    for (int j = 0; j < 6; ++j) {
        int c   = tid + 512 * j;
        int ckh = c / 1536;
        int r   = c % 1536;
        int f   = r >> 6;
        int l   = r & 63;
        srcB[j]    = bp + (size_t)(ckh * steps) * 12288 + f * 512 + l * 8;
        dstB[0][j] = &Bst[0][ckh][f * 512 + l * 8];
        dstB[1][j] = &Bst[1][ckh][f * 512 + l * 8];
    }

    #define STAGE(buf)                                                        \
        do {                                                                  \
            _Pragma("unroll")                                                 \
            for (int j = 0; j < 6; ++j) {                                     \
                gload_lds16(srcB[j], dstB[buf][j]);                           \
                srcB[j] += 12288;                                             \
            }                                                                 \
        } while (0)

    #define LOADA(d0, d1)                                                     \
        do {                                                                  \
            d0 = *reinterpret_cast<const float4*>(pa);                        \
            d1 = *reinterpret_cast<const float4*>(pa + 4);                    \
            pa += 32;                                                         \
        } while (0)

    #define COMPUTE(s0, s1, buf)                                              \
        do {                                                                  \
            float vals[8] = {s0.x, s0.y, s0.z, s0.w, s1.x, s1.y, s1.z, s1.w}; \
            ushort8 u1, u2, u3;                                               \
            _Pragma("unroll")                                                 \
            for (int j = 0; j < 8; ++j) {                                     \
                unsigned short h1, h2, h3;                                    \
                split3(vals[j], h1, h2, h3);                                  \
                u1[j] = h1; u2[j] = h2; u3[j] = h3;                           \
            }                                                                 \
            bf16x8 A1 = __builtin_bit_cast(bf16x8, u1);                       \
            bf16x8 A2 = __builtin_bit_cast(bf16x8, u2);                       \
            bf16x8 A3 = __builtin_bit_cast(bf16x8, u3);                       \
            const unsigned short* bb = &Bst[buf][kh][lane * 8];               \
            _Pragma("unroll")                                                 \
            for (int nt = 0; nt < NT; ++nt) {                                 \
                bf16x8 b1 = __builtin_bit_cast(bf16x8,                        \
                    *reinterpret_cast<const ushort8*>(bb + (nt * 3 + 0) * 512)); \
                bf16x8 b2 = __builtin_bit_cast(bf16x8,                        \
                    *reinterpret_cast<const ushort8*>(bb + (nt * 3 + 1) * 512)); \
                bf16x8 b3 = __builtin_bit_cast(bf16x8,                        \
                    *reinterpret_cast<const ushort8*>(bb + (nt * 3 + 2) * 512)); \
                f32x4 c = acc[nt];                                            \
                c = MFMA(A1, b1, c);                                          \
                c = MFMA(A1, b2, c);                                          \
                c = MFMA(A2, b1, c);                                          \
                c = MFMA(A2, b2, c);                                          \
                c = MFMA(A1, b3, c);                                          \
                c = MFMA(A3, b1, c);                                          \
                acc[nt] = c;                                                  \
            }                                                                 \
        } while (0)

    // ---- prologue: stage step 0, load A step 0 ----
    STAGE(0);
    float4 c0, c1, n0, n1;
    LOADA(c0, c1);
    __syncthreads();                       // vmcnt(0) drain -> buf0 ready

    // ---- main loop: one barrier per step; stage issued a full step ahead ----
    for (int s = 0; s < steps; s += 2) {
        STAGE(1);                          // step s+1 (always valid: s+1 <= steps-1)
        LOADA(n0, n1);                     // A step s+1
        COMPUTE(c0, c1, 0);                // step s
        __syncthreads();
        if (s + 2 < steps) {
            STAGE(0);                      // step s+2
            LOADA(c0, c1);
        }
        COMPUTE(n0, n1, 1);                // step s+1
        __syncthreads();
    }

    // ---- 2-way cross-half reduction in LDS ----
    // C/D frag (verified): reg r -> row=(lane>>4)*4+r, col=lane&15.
    if (kh == 0) {
        #pragma unroll
        for (int nt = 0; nt < NT; ++nt)
            #pragma unroll
            for (int r = 0; r < 4; ++r)
                Lred[mi * 16 + (lane >> 4) * 4 + r][nt * 16 + (lane & 15)] = acc[nt][r];
    }
    __syncthreads();
    if (kh == 1) {
        #pragma unroll
        for (int nt = 0; nt < NT; ++nt)
            #pragma unroll
            for (int r = 0; r < 4; ++r)
                Lred[mi * 16 + (lane >> 4) * 4 + r][nt * 16 + (lane & 15)] += acc[nt][r];
    }
    __syncthreads();

    // ---- per-token epilogue (proven path): one thread per token ----
    if (tid < BM) {
        const int t   = tid;
        const int tok = m0 + t;
        const float* nrow = noise + (size_t)tok * EE;
        float* lrow = out_logits + (size_t)tok * EE;

        float m = -3.4e38f;
        for (int e = 0; e < EE; ++e) {
            float gv = Lred[t][e];
            float nv = Lred[t][EE + e];
            float sp = fmaxf(nv, 0.f) + log1pf(expf(-fabsf(nv)));  // stable softplus
            float l  = fmaf(nrow[e], sp, gv);                      // NOISE_STD = 1
            lrow[e]  = l;
            Lred[t][e] = l;
            m = fmaxf(m, l);
        }

        float Z = 0.f;
        float p1 = -1.f, p2 = -1.f;
        int   i1 = 0,    i2 = 0;
        for (int e = 0; e < EE; ++e) {
            float p = expf(Lred[t][e] - m);
            Z += p;
            if (p > p1)      { p2 = p1; i2 = i1; p1 = p; i1 = e; }  // ties -> lower idx
            else if (p > p2) { p2 = p;  i2 = e; }
        }
        float q1 = p1 / Z, q2 = p2 / Z;
        float denom = q1 + q2 + 1e-9f;
        float w1 = q1 / denom, w2 = q2 / denom;

        out_idx[(size_t)tok * 2 + 0] = (float)i1;
        out_idx[(size_t)tok * 2 + 1] = (float)i2;

        float* grow = out_gate + (size_t)tok * EE;
        for (int e = 0; e < EE; ++e)
            grow[e] = (e == i1) ? w1 : ((e == i2) ? w2 : 0.f);
    }
}

extern "C" void kernel_launch(void* const* d_in, const int* in_sizes, int n_in,
                              void* d_out, int out_size, void* d_ws, size_t ws_size,
                              hipStream_t stream) {
    const float* hs    = (const float*)d_in[0];
    const float* noise = (const float*)d_in[1];
    const float* wg    = (const float*)d_in[2];
    const float* wn    = (const float*)d_in[3];

    const int Ntok = in_sizes[1] / EE;    // noise is [N][64]
    const int Hdim = in_sizes[2] / EE;    // w_gate is [64][H]

    float* out_gate   = (float*)d_out;
    float* out_idx    = out_gate + (size_t)Ntok * EE;
    float* out_logits = out_idx  + (size_t)Ntok * 2;

    unsigned short* bp = (unsigned short*)d_ws;   // needs (H/32)*8*3*512*2 = 3 MB

    // pack W into MFMA B-fragment layout (3 bf16 terms)
    int pairs = (Hdim / 32) * 8;
    hipLaunchKernelGGL(pack_b, dim3(pairs / 4), dim3(256), 0, stream, wg, wn, bp, Hdim);

    hipLaunchKernelGGL(router_mfma, dim3(Ntok / BM), dim3(512), 0, stream,
                       hs, noise, bp, out_gate, out_idx, out_logits, Ntok, Hdim);
}

// Round 7
// 161.798 us; speedup vs baseline: 6.4418x; 1.0340x over previous
//
#include <hip/hip_runtime.h>
#include <math.h>

// NoisyTopKRouter, round 7: un-starve the MFMA pipe.
//   - __launch_bounds__(512,2): VGPR cap 256 (2 waves/SIMD), room to hoist operands
//   - COMPUTE loads ALL 24 B-fragments to registers first, then 48 dense MFMAs
//   - native __bf16 casts (v_cvt_pk_bf16_f32) for the A split3: ~3x less VALU
//   - structure otherwise = round 6 (LDS-staged B, double-buffered, 1 barrier/step)
// Outputs (flat f32): gate_weights [N][64], top2 idx as float [N][2], logits [N][64].

typedef float   f32x4   __attribute__((ext_vector_type(4)));
typedef __bf16  bf16x8  __attribute__((ext_vector_type(8)));
typedef unsigned short ushort8 __attribute__((ext_vector_type(8)));

#define EE 64     // experts
#define E2 128    // gate+noise logit columns
#define NT 8      // 16-col n-tiles (128 cols)
#define BM 64     // tokens per block

__device__ __forceinline__ unsigned short bf16_rne(float f) {
    unsigned int u = __float_as_uint(f);
    u += 0x7fffu + ((u >> 16) & 1u);
    return (unsigned short)(u >> 16);
}
__device__ __forceinline__ float bf16_f32(unsigned short h) {
    return __uint_as_float(((unsigned int)h) << 16);
}
__device__ __forceinline__ void split3(float a, unsigned short& h1,
                                       unsigned short& h2, unsigned short& h3) {
    h1 = bf16_rne(a);
    float r  = a - bf16_f32(h1);     // exact
    h2 = bf16_rne(r);
    float r2 = r - bf16_f32(h2);     // exact
    h3 = bf16_rne(r2);
}

__device__ __forceinline__ void gload_lds16(const void* g, void* l) {
    __builtin_amdgcn_global_load_lds(
        (const __attribute__((address_space(1))) void*)g,
        (__attribute__((address_space(3))) void*)l, 16, 0, 0);
}

// ---- pre-kernel: pack W (gate cols 0..63, noise cols 64..127) into B-frag order.
// Fragment (16x16x32 bf16, verified): lane l holds col=l&15, k=(l>>4)*8+j.
// Packed ushort addr: ((ks*8 + nt)*3 + term)*512 + lane*8 + j   (ks = k/32)
__global__ __launch_bounds__(256) void pack_b(
    const float* __restrict__ wg, const float* __restrict__ wn,
    unsigned short* __restrict__ bp, int Hdim)
{
    int pair = blockIdx.x * 4 + (threadIdx.x >> 6);   // (ks, nt)
    int l    = threadIdx.x & 63;
    int ks   = pair >> 3;
    int nt   = pair & 7;
    int col  = nt * 16 + (l & 15);
    int k    = ks * 32 + ((l >> 4) * 8);
    const float* wrow = (col < EE) ? (wg + (size_t)col * Hdim)
                                   : (wn + (size_t)(col - EE) * Hdim);
    float4 v0 = *reinterpret_cast<const float4*>(wrow + k);
    float4 v1 = *reinterpret_cast<const float4*>(wrow + k + 4);
    float vals[8] = {v0.x, v0.y, v0.z, v0.w, v1.x, v1.y, v1.z, v1.w};
    ushort8 t1, t2, t3;
    #pragma unroll
    for (int j = 0; j < 8; ++j) {
        unsigned short a, b, c;
        split3(vals[j], a, b, c);
        t1[j] = a; t2[j] = b; t3[j] = c;
    }
    size_t base = ((size_t)(ks * 8 + nt) * 3) * 512 + (size_t)l * 8;
    *reinterpret_cast<ushort8*>(bp + base        ) = t1;
    *reinterpret_cast<ushort8*>(bp + base + 512  ) = t2;
    *reinterpret_cast<ushort8*>(bp + base + 1024 ) = t3;
}

#define MFMA(a, b, c) __builtin_amdgcn_mfma_f32_16x16x32_bf16((a), (b), (c), 0, 0, 0)

__global__ __launch_bounds__(512, 2) void router_mfma(
    const float* __restrict__ hs,
    const float* __restrict__ noise,
    const unsigned short* __restrict__ bp,
    float* __restrict__ out_gate,
    float* __restrict__ out_idx,
    float* __restrict__ out_logits,
    int Ntok, int Hdim)
{
    // B staging: [dbuf][kh][frag(0..23)*512 + lane*8 + j] ushorts -> 96 KB
    __shared__ unsigned short Bst[2][2][24 * 512];
    __shared__ float Lred[BM][E2 + 5];   // stride 133 -> conflict-free scalar reads

    const int tid  = threadIdx.x;
    const int lane = tid & 63;
    const int w    = tid >> 6;           // wave 0..7
    const int kh   = w >> 2;             // k-half 0..1
    const int mi   = w & 3;              // m-tile 0..3
    const int m0   = blockIdx.x * BM;

    const int khalf = Hdim >> 1;         // 2048
    const int steps = khalf >> 5;        // 64 (even)

    f32x4 acc[NT];
    #pragma unroll
    for (int nt = 0; nt < NT; ++nt) acc[nt] = f32x4{0.f, 0.f, 0.f, 0.f};

    // ---- A source: lane l covers row (l&15) of this wave's m-tile, k-octet (l>>4)*8
    const float* pa = hs + (size_t)(m0 + mi * 16 + (lane & 15)) * Hdim
                         + (size_t)kh * khalf + ((lane >> 4) * 8);

    // ---- B stage chunks: 3072 x 16B per step; chunk c = tid + 512*j.
    //      kh' = c/1536 and frag f = (c%1536)/64 are wave-uniform; lane varies -> lane*16B.
    const unsigned short* srcB[6];
    unsigned short* dstB[2][6];
    #pragma unroll
    for (int j = 0; j < 6; ++j) {
        int c   = tid + 512 * j;
        int ckh = c / 1536;
        int r   = c % 1536;
        int f   = r >> 6;
        int l   = r & 63;
        srcB[j]    = bp + (size_t)(ckh * steps) * 12288 + f * 512 + l * 8;
        dstB[0][j] = &Bst[0][ckh][f * 512 + l * 8];
        dstB[1][j] = &Bst[1][ckh][f * 512 + l * 8];
    }

    #define STAGE(buf)                                                        \
        do {                                                                  \
            _Pragma("unroll")                                                 \
            for (int j = 0; j < 6; ++j) {                                     \
                gload_lds16(srcB[j], dstB[buf][j]);                           \
                srcB[j] += 12288;                                             \
            }                                                                 \
        } while (0)

    #define LOADA(d0, d1)                                                     \
        do {                                                                  \
            d0 = *reinterpret_cast<const float4*>(pa);                        \
            d1 = *reinterpret_cast<const float4*>(pa + 4);                    \
            pa += 32;                                                         \
        } while (0)

    // COMPUTE: split A (native bf16 cvt), hoist ALL 24 B frags, then dense MFMA.
    #define COMPUTE(s0, s1, buf)                                              \
        do {                                                                  \
            float vals[8] = {s0.x, s0.y, s0.z, s0.w, s1.x, s1.y, s1.z, s1.w}; \
            bf16x8 A1, A2, A3;                                                \
            _Pragma("unroll")                                                 \
            for (int j = 0; j < 8; ++j) {                                     \
                float a  = vals[j];                                           \
                __bf16 h1 = (__bf16)a;                                        \
                float r  = a - (float)h1;                                     \
                __bf16 h2 = (__bf16)r;                                        \
                float r2 = r - (float)h2;                                     \
                __bf16 h3 = (__bf16)r2;                                       \
                A1[j] = h1; A2[j] = h2; A3[j] = h3;                           \
            }                                                                 \
            const unsigned short* bb = &Bst[buf][kh][lane * 8];               \
            ushort8 bf[24];                                                   \
            _Pragma("unroll")                                                 \
            for (int f = 0; f < 24; ++f)                                      \
                bf[f] = *reinterpret_cast<const ushort8*>(bb + f * 512);      \
            _Pragma("unroll")                                                 \
            for (int nt = 0; nt < NT; ++nt) {                                 \
                bf16x8 b1 = __builtin_bit_cast(bf16x8, bf[nt * 3 + 0]);       \
                bf16x8 b2 = __builtin_bit_cast(bf16x8, bf[nt * 3 + 1]);       \
                bf16x8 b3 = __builtin_bit_cast(bf16x8, bf[nt * 3 + 2]);       \
                f32x4 c = acc[nt];                                            \
                c = MFMA(A1, b1, c);                                          \
                c = MFMA(A1, b2, c);                                          \
                c = MFMA(A2, b1, c);                                          \
                c = MFMA(A2, b2, c);                                          \
                c = MFMA(A1, b3, c);                                          \
                c = MFMA(A3, b1, c);                                          \
                acc[nt] = c;                                                  \
            }                                                                 \
        } while (0)

    // ---- prologue: stage step 0, load A step 0 ----
    STAGE(0);
    float4 c0, c1, n0, n1;
    LOADA(c0, c1);
    __syncthreads();                       // vmcnt(0) drain -> buf0 ready

    // ---- main loop: one barrier per step; stage issued a full step ahead ----
    for (int s = 0; s < steps; s += 2) {
        STAGE(1);                          // step s+1
        LOADA(n0, n1);                     // A step s+1
        COMPUTE(c0, c1, 0);                // step s
        __syncthreads();
        if (s + 2 < steps) {
            STAGE(0);                      // step s+2
            LOADA(c0, c1);
        }
        COMPUTE(n0, n1, 1);                // step s+1
        __syncthreads();
    }

    // ---- 2-way cross-half reduction in LDS ----
    // C/D frag (verified): reg r -> row=(lane>>4)*4+r, col=lane&15.
    if (kh == 0) {
        #pragma unroll
        for (int nt = 0; nt < NT; ++nt)
            #pragma unroll
            for (int r = 0; r < 4; ++r)
                Lred[mi * 16 + (lane >> 4) * 4 + r][nt * 16 + (lane & 15)] = acc[nt][r];
    }
    __syncthreads();
    if (kh == 1) {
        #pragma unroll
        for (int nt = 0; nt < NT; ++nt)
            #pragma unroll
            for (int r = 0; r < 4; ++r)
                Lred[mi * 16 + (lane >> 4) * 4 + r][nt * 16 + (lane & 15)] += acc[nt][r];
    }
    __syncthreads();

    // ---- per-token epilogue (proven path): one thread per token ----
    if (tid < BM) {
        const int t   = tid;
        const int tok = m0 + t;
        const float* nrow = noise + (size_t)tok * EE;
        float* lrow = out_logits + (size_t)tok * EE;

        float m = -3.4e38f;
        for (int e = 0; e < EE; ++e) {
            float gv = Lred[t][e];
            float nv = Lred[t][EE + e];
            float sp = fmaxf(nv, 0.f) + log1pf(expf(-fabsf(nv)));  // stable softplus
            float l  = fmaf(nrow[e], sp, gv);                      // NOISE_STD = 1
            lrow[e]  = l;
            Lred[t][e] = l;
            m = fmaxf(m, l);
        }

        float Z = 0.f;
        float p1 = -1.f, p2 = -1.f;
        int   i1 = 0,    i2 = 0;
        for (int e = 0; e < EE; ++e) {
            float p = expf(Lred[t][e] - m);
            Z += p;
            if (p > p1)      { p2 = p1; i2 = i1; p1 = p; i1 = e; }  // ties -> lower idx
            else if (p > p2) { p2 = p;  i2 = e; }
        }
        float q1 = p1 / Z, q2 = p2 / Z;
        float denom = q1 + q2 + 1e-9f;
        float w1 = q1 / denom, w2 = q2 / denom;

        out_idx[(size_t)tok * 2 + 0] = (float)i1;
        out_idx[(size_t)tok * 2 + 1] = (float)i2;

        float* grow = out_gate + (size_t)tok * EE;
        for (int e = 0; e < EE; ++e)
            grow[e] = (e == i1) ? w1 : ((e == i2) ? w2 : 0.f);
    }
}

extern "C" void kernel_launch(void* const* d_in, const int* in_sizes, int n_in,
                              void* d_out, int out_size, void* d_ws, size_t ws_size,
                              hipStream_t stream) {
    const float* hs    = (const float*)d_in[0];
    const float* noise = (const float*)d_in[1];
    const float* wg    = (const float*)d_in[2];
    const float* wn    = (const float*)d_in[3];

    const int Ntok = in_sizes[1] / EE;    // noise is [N][64]
    const int Hdim = in_sizes[2] / EE;    // w_gate is [64][H]

    float* out_gate   = (float*)d_out;
    float* out_idx    = out_gate + (size_t)Ntok * EE;
    float* out_logits = out_idx  + (size_t)Ntok * 2;

    unsigned short* bp = (unsigned short*)d_ws;   // needs (H/32)*8*3*512*2 = 3 MB

    // pack W into MFMA B-fragment layout (3 bf16 terms)
    int pairs = (Hdim / 32) * 8;
    hipLaunchKernelGGL(pack_b, dim3(pairs / 4), dim3(256), 0, stream, wg, wn, bp, Hdim);

    hipLaunchKernelGGL(router_mfma, dim3(Ntok / BM), dim3(512), 0, stream,
                       hs, noise, bp, out_gate, out_idx, out_logits, Ntok, Hdim);
}